// Round 1
// 147.319 us; speedup vs baseline: 1.0101x; 1.0101x over previous
//
#include <hip/hip_runtime.h>
#include <stdint.h>

// EdgeNetwork, round 6: kill the scratch round-trip in msg_mfma_kernel.
// r5's `float bv[16]` was indexed by runtime `2*c+hb` (hb is lane-dependent)
// -> alloca forced to SCRATCH (VGPR_Count=56 < ~75 minimum live set proved it).
// Every group did 16 scratch stores + 8 scattered scratch loads = the latency
// wall (65us @ 14% HBM / 3% MFMA / 38% VALU). Fix: select bond parity values
// via ternaries on named float4 components (8 v_cndmask, hb is loop-invariant
// per lane), so the whole kernel lives in registers. __launch_bounds__(256,4)
// caps allocator at 128 VGPR (4 waves/SIMD).
// Also: reduce_kernel 8 -> 32 threads/atom (2500 -> 10000 waves) for latency
// hiding on the scattered slot reads.
// History: r1 630us -> r2 CSR 333 -> r3 MFMA 190 -> r4 fused-rank binning 150
// -> r5 packed-store/contention fix 148.8 (msg 65us).

constexpr int DIM  = 16;
constexpr int CAP  = 64;     // slots per atom; P(deg>64) ~ 1e-8 at Poisson(32)
constexpr int CSTR = 16;     // counts stride (ints) = one 64B line per atom
constexpr int OFLOW_CAP = 65536;
constexpr int GPW  = 4;      // 16-edge groups per wave, fully unrolled

using frag_ab = __attribute__((ext_vector_type(8))) short;   // 8 bf16
using frag_cd = __attribute__((ext_vector_type(4))) float;   // 4 f32
union ABPack { frag_ab f; uint32_t u[4]; };

__device__ __forceinline__ uint32_t pack_bf16_2(float lo, float hi) {
    // one v_perm_b32: truncate-to-bf16 pair, lo in low 16 bits
    return __builtin_amdgcn_perm(__float_as_uint(hi), __float_as_uint(lo), 0x07060302u);
}

// ---- msg kernel: fused rank + MFMA(T) + packed bf16 store into stride slot
__global__ __launch_bounds__(256, 4) void msg_mfma_kernel(
    const float* __restrict__ atom, const float* __restrict__ bond,
    const int*   __restrict__ pair, const float* __restrict__ kern,
    const float* __restrict__ bias,
    int* __restrict__ counts, int* __restrict__ oflow_cnt, int* __restrict__ oflow,
    uint16_t* __restrict__ msgs, int n_edges, int n_groups)
{
    const int wave = (int)((blockIdx.x * blockDim.x + threadIdx.x) >> 6);
    const int lane = threadIdx.x & 63;
    const int g0 = wave * GPW;
    if (g0 >= n_groups) return;

    const int col  = lane & 15;        // A(W): output row i | B(Z): edge e | D: col e
    const int quad = lane >> 4;        // 0..3
    const int hb   = quad >> 1;        // kb parity within chunk (0/1, fixed per lane)
    const int j0   = (quad & 1) * 8;   // neigh sub-range

    // W fragments as operand-0 (A[m=i][k]); identical loads to r3/r4/r5 (verified)
    frag_ab wfrag[8];
#pragma unroll
    for (int c = 0; c < 8; ++c) {
        const float* wp = kern + (2 * c + hb) * 256 + col * 16 + j0;
        float4 w0 = *(const float4*)wp;
        float4 w1 = *(const float4*)(wp + 4);
        ABPack p;
        p.u[0] = pack_bf16_2(w0.x, w0.y);
        p.u[1] = pack_bf16_2(w0.z, w0.w);
        p.u[2] = pack_bf16_2(w1.x, w1.y);
        p.u[3] = pack_bf16_2(w1.z, w1.w);
        wfrag[c] = p.f;
    }
    frag_ab bias_a;
    {
        ABPack p; p.u[0] = p.u[1] = p.u[2] = p.u[3] = 0;
        if (hb == 0) {
            const float* bp2 = bias + col * 16 + j0;
            float4 w0 = *(const float4*)bp2;
            float4 w1 = *(const float4*)(bp2 + 4);
            p.u[0] = pack_bf16_2(w0.x, w0.y);
            p.u[1] = pack_bf16_2(w0.z, w0.w);
            p.u[2] = pack_bf16_2(w1.x, w1.y);
            p.u[3] = pack_bf16_2(w1.z, w1.w);
        }
        bias_a = p.f;
    }

#pragma unroll
    for (int u = 0; u < GPW; ++u) {
        const int g = g0 + u;
        if (g < n_groups) {
            const int eb = g << 4;
            const int e  = eb + col;
            const int ec = min(e, n_edges - 1);

            const int2 pr = ((const int2*)pair)[ec];        // x=dst, y=src

            // fused rank: quad 0 lanes only; 64B-strided counters
            int slot = -1;
            if (quad == 0 && e < n_edges) {
                int r = atomicAdd(&counts[pr.x * CSTR], 1);
                if (r < CAP) {
                    slot = pr.x * CAP + r;
                } else {
                    int oi = atomicAdd(oflow_cnt, 1);
                    if (oi < OFLOW_CAP) oflow[oi] = e;
                }
            }

            // neigh slice [j0, j0+8) for this lane's edge
            const float* np_ = atom + (size_t)pr.y * DIM + j0;
            float4 n0 = *(const float4*)np_;
            float4 n1 = *(const float4*)(np_ + 4);
            float nb[8] = {n0.x, n0.y, n0.z, n0.w, n1.x, n1.y, n1.z, n1.w};

            // bond row as NAMED registers; parity-select with ternaries on hb
            // (constant-indexed bks[] -> SROA keeps it in VGPRs; r5's dynamic
            //  bv[2c+hb] forced the array to scratch)
            const float4* bp = (const float4*)(bond + (size_t)ec * DIM);
            float4 b0 = bp[0], b1 = bp[1], b2 = bp[2], b3 = bp[3];
            float bks[8];
            bks[0] = hb ? b0.y : b0.x;
            bks[1] = hb ? b0.w : b0.z;
            bks[2] = hb ? b1.y : b1.x;
            bks[3] = hb ? b1.w : b1.z;
            bks[4] = hb ? b2.y : b2.x;
            bks[5] = hb ? b2.w : b2.z;
            bks[6] = hb ? b3.y : b3.x;
            bks[7] = hb ? b3.w : b3.z;

            frag_cd acc = {0.f, 0.f, 0.f, 0.f};
#pragma unroll
            for (int c = 0; c < 8; ++c) {
                const float bk = bks[c];
                ABPack z;
                z.u[0] = pack_bf16_2(bk * nb[0], bk * nb[1]);
                z.u[1] = pack_bf16_2(bk * nb[2], bk * nb[3]);
                z.u[2] = pack_bf16_2(bk * nb[4], bk * nb[5]);
                z.u[3] = pack_bf16_2(bk * nb[6], bk * nb[7]);
                // operand swap: D = W^T Z^T -> lane holds 4 consecutive cols
                acc = __builtin_amdgcn_mfma_f32_16x16x32_bf16(wfrag[c], z.f, acc, 0, 0, 0);
            }
            { // bias chunk (k<16 half only)
                ABPack z; z.u[0] = z.u[1] = z.u[2] = z.u[3] = 0;
                if (hb == 0) {
                    z.u[0] = pack_bf16_2(nb[0], nb[1]);
                    z.u[1] = pack_bf16_2(nb[2], nb[3]);
                    z.u[2] = pack_bf16_2(nb[4], nb[5]);
                    z.u[3] = pack_bf16_2(nb[6], nb[7]);
                }
                acc = __builtin_amdgcn_mfma_f32_16x16x32_bf16(bias_a, z.f, acc, 0, 0, 0);
            }

            // D^T: lane (quad,col) holds msgs[e=col][i=quad*4 .. +3]
            const int s = __shfl(slot, col, 64);   // from quad0 lane `col`
            if (s >= 0) {
                uint2 pkd;
                pkd.x = pack_bf16_2(acc[0], acc[1]);
                pkd.y = pack_bf16_2(acc[2], acc[3]);
                *(uint2*)(msgs + (size_t)s * DIM + quad * 4) = pkd;  // one 8B store
            }
        }
    }
}

// ---- reduce: 32 threads/atom over fixed-stride bf16 slots, atomic-free
// (r5 used 8 threads/atom = 2500 waves total ~2.4/SIMD; too little TLP to
//  hide the scattered slot-read latency. Now 10000 waves, ~4 iters/thread,
//  iteration 0 of each atom reads 256B contiguous.)
__global__ __launch_bounds__(256) void reduce_kernel(
    const uint16_t* __restrict__ msgs, const int* __restrict__ counts,
    float* __restrict__ out, int n_atoms)
{
    int t = blockIdx.x * blockDim.x + threadIdx.x;
    int a = t >> 5;
    if (a >= n_atoms) return;
    int c = t & 3;          // 4-col chunk (8B)
    int q = (t >> 2) & 7;   // 8-way split of the message list

    int cnt = min(counts[a * CSTR], CAP);
    const uint32_t* base = (const uint32_t*)(msgs + (size_t)a * CAP * DIM);

    float4 acc = make_float4(0.f, 0.f, 0.f, 0.f);
    for (int j = q; j < cnt; j += 8) {
        uint2 v = *(const uint2*)(base + j * 8 + c * 2);     // 4 bf16 = 8 B
        acc.x += __uint_as_float(v.x << 16);
        acc.y += __uint_as_float(v.x & 0xFFFF0000u);
        acc.z += __uint_as_float(v.y << 16);
        acc.w += __uint_as_float(v.y & 0xFFFF0000u);
    }
    // combine the 8-way q split (lane bits 2..4)
    acc.x += __shfl_xor(acc.x, 4);  acc.y += __shfl_xor(acc.y, 4);
    acc.z += __shfl_xor(acc.z, 4);  acc.w += __shfl_xor(acc.w, 4);
    acc.x += __shfl_xor(acc.x, 8);  acc.y += __shfl_xor(acc.y, 8);
    acc.z += __shfl_xor(acc.z, 8);  acc.w += __shfl_xor(acc.w, 8);
    acc.x += __shfl_xor(acc.x, 16); acc.y += __shfl_xor(acc.y, 16);
    acc.z += __shfl_xor(acc.z, 16); acc.w += __shfl_xor(acc.w, 16);
    if (q == 0)
        ((float4*)(out + (size_t)a * DIM))[c] = acc;
}

// ---- overflow fix-up (normally 0 edges): scalar f32 + atomicAdd, AFTER reduce
__global__ __launch_bounds__(256) void oflow_kernel(
    const float* __restrict__ atom, const float* __restrict__ bond,
    const int*   __restrict__ pair, const float* __restrict__ kern,
    const float* __restrict__ bias,
    const int* __restrict__ oflow_cnt, const int* __restrict__ oflow,
    float* __restrict__ out, int n_edges)
{
    int n = min(*oflow_cnt, OFLOW_CAP);
    for (int i = blockIdx.x * blockDim.x + threadIdx.x; i < n;
         i += gridDim.x * blockDim.x) {
        int e   = oflow[i];
        int dst = pair[2 * e + 0];
        int src = pair[2 * e + 1];
        float neigh[DIM], bnd[DIM], acc[DIM];
        for (int q = 0; q < DIM; ++q) neigh[q] = atom[(size_t)src * DIM + q];
        for (int q = 0; q < DIM; ++q) bnd[q]   = bond[(size_t)e * DIM + q];
#pragma unroll
        for (int ii = 0; ii < DIM; ++ii) {
            float d = 0.f;
#pragma unroll
            for (int j = 0; j < DIM; ++j) d = fmaf(bias[ii * DIM + j], neigh[j], d);
            acc[ii] = d;
        }
#pragma unroll 1
        for (int k = 0; k < DIM; ++k) {
            const float bk = bnd[k];
            const float* Kr = kern + k * (DIM * DIM);
#pragma unroll
            for (int ii = 0; ii < DIM; ++ii) {
                float d = 0.f;
#pragma unroll
                for (int j = 0; j < DIM; ++j) d = fmaf(Kr[ii * DIM + j], neigh[j], d);
                acc[ii] = fmaf(bk, d, acc[ii]);
            }
        }
#pragma unroll
        for (int ii = 0; ii < DIM; ++ii) atomicAdd(&out[(size_t)dst * DIM + ii], acc[ii]);
    }
}

// ---- safety fallback if ws too small (round-1 structure)
__global__ __launch_bounds__(256) void edge_atomic_kernel(
    const float* __restrict__ atom, const float* __restrict__ bond,
    const int*   __restrict__ pair, const float* __restrict__ kern,
    const float* __restrict__ bias, float* __restrict__ out, int n_edges)
{
    int e = blockIdx.x * blockDim.x + threadIdx.x;
    if (e >= n_edges) return;
    int dst = pair[2 * e + 0];
    int src = pair[2 * e + 1];
    float neigh[DIM], bnd[DIM], acc[DIM];
    for (int q = 0; q < DIM; ++q) neigh[q] = atom[(size_t)src * DIM + q];
    for (int q = 0; q < DIM; ++q) bnd[q]   = bond[(size_t)e * DIM + q];
#pragma unroll
    for (int i = 0; i < DIM; ++i) {
        float d = 0.f;
#pragma unroll
        for (int j = 0; j < DIM; ++j) d = fmaf(bias[i * DIM + j], neigh[j], d);
        acc[i] = d;
    }
#pragma unroll 1
    for (int k = 0; k < DIM; ++k) {
        const float bk = bnd[k];
        const float* Kr = kern + k * (DIM * DIM);
#pragma unroll
        for (int i = 0; i < DIM; ++i) {
            float d = 0.f;
#pragma unroll
            for (int j = 0; j < DIM; ++j) d = fmaf(Kr[i * DIM + j], neigh[j], d);
            acc[i] = fmaf(bk, d, acc[i]);
        }
    }
#pragma unroll
    for (int i = 0; i < DIM; ++i) atomicAdd(&out[(size_t)dst * DIM + i], acc[i]);
}

extern "C" void kernel_launch(void* const* d_in, const int* in_sizes, int n_in,
                              void* d_out, int out_size, void* d_ws, size_t ws_size,
                              hipStream_t stream)
{
    const float* atom = (const float*)d_in[0];   // (20000,16) f32
    const float* bond = (const float*)d_in[1];   // (640000,16) f32
    const int*   pair = (const int*)d_in[2];     // (640000,2) i32 [dst, src]
    const float* kern = (const float*)d_in[3];   // (16,256) f32
    const float* bias = (const float*)d_in[4];   // (256,) f32
    float*       out  = (float*)d_out;           // (20000,16) f32

    const int n_edges = in_sizes[1] / DIM;       // 640000
    const int n_atoms = in_sizes[0] / DIM;       // 20000

    // ws: counts[n_atoms*CSTR] | oflow_cnt[1] | oflow[OFLOW_CAP] | 64B | msgs bf16
    size_t counts_off = 0;
    size_t ocnt_off   = counts_off + (size_t)n_atoms * CSTR * sizeof(int);
    size_t oflow_off  = ocnt_off + sizeof(int);
    size_t msgs_off   = (oflow_off + (size_t)OFLOW_CAP * sizeof(int) + 63) & ~(size_t)63;
    size_t needed     = msgs_off + (size_t)n_atoms * CAP * DIM * sizeof(uint16_t);

    const int threads = 256;

    if (ws_size >= needed) {
        int*      counts    = (int*)((char*)d_ws + counts_off);
        int*      oflow_cnt = (int*)((char*)d_ws + ocnt_off);
        int*      oflow     = (int*)((char*)d_ws + oflow_off);
        uint16_t* msgs      = (uint16_t*)((char*)d_ws + msgs_off);

        // zero counts (padded) + oflow counter in one contiguous memset
        hipMemsetAsync(counts, 0, (size_t)n_atoms * CSTR * sizeof(int) + sizeof(int),
                       stream);

        const int n_groups = (n_edges + 15) / 16;
        const int waves    = (n_groups + GPW - 1) / GPW;
        const int mblocks  = (waves * 64 + threads - 1) / threads;
        msg_mfma_kernel<<<mblocks, threads, 0, stream>>>(
            atom, bond, pair, kern, bias, counts, oflow_cnt, oflow, msgs,
            n_edges, n_groups);

        const int rthreads = n_atoms * 32;
        reduce_kernel<<<(rthreads + threads - 1) / threads, threads, 0, stream>>>(
            msgs, counts, out, n_atoms);

        oflow_kernel<<<8, threads, 0, stream>>>(
            atom, bond, pair, kern, bias, oflow_cnt, oflow, out, n_edges);
    } else {
        hipMemsetAsync(out, 0, (size_t)out_size * sizeof(float), stream);
        edge_atomic_kernel<<<(n_edges + threads - 1) / threads, threads, 0, stream>>>(
            atom, bond, pair, kern, bias, out, n_edges);
    }
}

// Round 2
// 136.452 us; speedup vs baseline: 1.0906x; 1.0796x over previous
//
#include <hip/hip_runtime.h>
#include <stdint.h>

// EdgeNetwork, round 7: break the vmcnt-accounting serialization.
// r6 showed VALUBusy 38->16% with NO time change -> latency-bound, not VALU.
// VGPR_Count=56 proved the compiler SERIALIZED the 4 unrolled groups (register
// reuse, no cross-group pipelining), and per group the program order was
// pair -> atomicAdd -> gathers -> compute. vmcnt completes IN ORDER, so every
// gather wait also waited out the contended counter atomic (~1000cy): 4 serial
// (atomic+gather+mfma) chains per wave = ~940 cyc/group/CU observed.
// Fix: explicit 5-phase staging across all GPW groups:
//   P1 pair x4 -> P2 atom/bond gathers x4 -> P3 atomicAdd x4 (ticket only,
//   result NOT consumed) -> P4 all compute -> P5 slot resolve + shfl + store.
// Atomics issue AFTER gathers (gather waits no longer queue behind them) and
// their results are read only after all MFMAs (latency hidden under compute).
// __launch_bounds__(256,2) gives ~175 regs of staging room, 8 waves/CU.
// History: r1 630 -> r2 CSR 333 -> r3 MFMA 190 -> r4 binning 150 -> r5 packed
// store 148.8 (msg 65) -> r6 scratch-fix 147.3 (msg 61, VALU halved, latency
// wall identified).

constexpr int DIM  = 16;
constexpr int CAP  = 64;     // slots per atom; P(deg>64) ~ 1e-8 at Poisson(32)
constexpr int CSTR = 16;     // counts stride (ints) = one 64B line per atom
constexpr int OFLOW_CAP = 65536;
constexpr int GPW  = 4;      // 16-edge groups per wave, fully unrolled

using frag_ab = __attribute__((ext_vector_type(8))) short;   // 8 bf16
using frag_cd = __attribute__((ext_vector_type(4))) float;   // 4 f32
union ABPack { frag_ab f; uint32_t u[4]; };

__device__ __forceinline__ uint32_t pack_bf16_2(float lo, float hi) {
    // one v_perm_b32: truncate-to-bf16 pair, lo in low 16 bits
    return __builtin_amdgcn_perm(__float_as_uint(hi), __float_as_uint(lo), 0x07060302u);
}

// ---- msg kernel: fused rank + MFMA(T) + packed bf16 store into stride slot
__global__ __launch_bounds__(256, 2) void msg_mfma_kernel(
    const float* __restrict__ atom, const float* __restrict__ bond,
    const int*   __restrict__ pair, const float* __restrict__ kern,
    const float* __restrict__ bias,
    int* __restrict__ counts, int* __restrict__ oflow_cnt, int* __restrict__ oflow,
    uint16_t* __restrict__ msgs, int n_edges, int n_groups)
{
    const int wave = (int)((blockIdx.x * blockDim.x + threadIdx.x) >> 6);
    const int lane = threadIdx.x & 63;
    const int g0 = wave * GPW;
    if (g0 >= n_groups) return;

    const int col  = lane & 15;        // A(W): output row i | B(Z): edge e | D: col e
    const int quad = lane >> 4;        // 0..3
    const int hb   = quad >> 1;        // kb parity within chunk (0/1, fixed per lane)
    const int j0   = (quad & 1) * 8;   // neigh sub-range

    // ---- P1: pair loads for all groups (unguarded; ec clamp makes them safe)
    int  e_[GPW];
    int  ec_[GPW];
    int2 pr_[GPW];
#pragma unroll
    for (int u = 0; u < GPW; ++u) {
        e_[u]  = ((g0 + u) << 4) + col;
        ec_[u] = min(e_[u], n_edges - 1);
        pr_[u] = ((const int2*)pair)[ec_[u]];
    }

    // W fragments (L2-hot broadcast; overlaps with P1 latency)
    frag_ab wfrag[8];
#pragma unroll
    for (int c = 0; c < 8; ++c) {
        const float* wp = kern + (2 * c + hb) * 256 + col * 16 + j0;
        float4 w0 = *(const float4*)wp;
        float4 w1 = *(const float4*)(wp + 4);
        ABPack p;
        p.u[0] = pack_bf16_2(w0.x, w0.y);
        p.u[1] = pack_bf16_2(w0.z, w0.w);
        p.u[2] = pack_bf16_2(w1.x, w1.y);
        p.u[3] = pack_bf16_2(w1.z, w1.w);
        wfrag[c] = p.f;
    }
    frag_ab bias_a;
    {
        ABPack p; p.u[0] = p.u[1] = p.u[2] = p.u[3] = 0;
        if (hb == 0) {
            const float* bp2 = bias + col * 16 + j0;
            float4 w0 = *(const float4*)bp2;
            float4 w1 = *(const float4*)(bp2 + 4);
            p.u[0] = pack_bf16_2(w0.x, w0.y);
            p.u[1] = pack_bf16_2(w0.z, w0.w);
            p.u[2] = pack_bf16_2(w1.x, w1.y);
            p.u[3] = pack_bf16_2(w1.z, w1.w);
        }
        bias_a = p.f;
    }

    // ---- P2: neigh + bond gathers for all groups (24 independent loads)
    float4 n0_[GPW], n1_[GPW];
    float4 b0_[GPW], b1_[GPW], b2_[GPW], b3_[GPW];
#pragma unroll
    for (int u = 0; u < GPW; ++u) {
        const float* np_ = atom + (size_t)pr_[u].y * DIM + j0;
        n0_[u] = *(const float4*)np_;
        n1_[u] = *(const float4*)(np_ + 4);
        const float4* bp = (const float4*)(bond + (size_t)ec_[u] * DIM);
        b0_[u] = bp[0]; b1_[u] = bp[1]; b2_[u] = bp[2]; b3_[u] = bp[3];
    }

    // ---- P3: rank atomics, ticket ONLY (result consumed in P5, after compute;
    //          issued after gathers so gather vmcnt waits don't include them)
    int r_[GPW];
#pragma unroll
    for (int u = 0; u < GPW; ++u) {
        r_[u] = CAP;                       // inactive lanes -> overflow-free no-op
        if (quad == 0 && e_[u] < n_edges)
            r_[u] = atomicAdd(&counts[pr_[u].x * CSTR], 1);
    }

    // ---- P4: pack + MFMA for all groups (waits only on P2 loads)
    frag_cd acc_[GPW];
#pragma unroll
    for (int u = 0; u < GPW; ++u) {
        float nb[8] = {n0_[u].x, n0_[u].y, n0_[u].z, n0_[u].w,
                       n1_[u].x, n1_[u].y, n1_[u].z, n1_[u].w};
        // parity-select bond values with ternaries (hb loop-invariant per lane;
        // constant indexing keeps everything in VGPRs)
        float bks[8];
        bks[0] = hb ? b0_[u].y : b0_[u].x;
        bks[1] = hb ? b0_[u].w : b0_[u].z;
        bks[2] = hb ? b1_[u].y : b1_[u].x;
        bks[3] = hb ? b1_[u].w : b1_[u].z;
        bks[4] = hb ? b2_[u].y : b2_[u].x;
        bks[5] = hb ? b2_[u].w : b2_[u].z;
        bks[6] = hb ? b3_[u].y : b3_[u].x;
        bks[7] = hb ? b3_[u].w : b3_[u].z;

        frag_cd acc = {0.f, 0.f, 0.f, 0.f};
#pragma unroll
        for (int c = 0; c < 8; ++c) {
            const float bk = bks[c];
            ABPack z;
            z.u[0] = pack_bf16_2(bk * nb[0], bk * nb[1]);
            z.u[1] = pack_bf16_2(bk * nb[2], bk * nb[3]);
            z.u[2] = pack_bf16_2(bk * nb[4], bk * nb[5]);
            z.u[3] = pack_bf16_2(bk * nb[6], bk * nb[7]);
            // operand swap: D = W^T Z^T -> lane holds 4 consecutive cols
            acc = __builtin_amdgcn_mfma_f32_16x16x32_bf16(wfrag[c], z.f, acc, 0, 0, 0);
        }
        { // bias chunk (k<16 half only)
            ABPack z; z.u[0] = z.u[1] = z.u[2] = z.u[3] = 0;
            if (hb == 0) {
                z.u[0] = pack_bf16_2(nb[0], nb[1]);
                z.u[1] = pack_bf16_2(nb[2], nb[3]);
                z.u[2] = pack_bf16_2(nb[4], nb[5]);
                z.u[3] = pack_bf16_2(nb[6], nb[7]);
            }
            acc = __builtin_amdgcn_mfma_f32_16x16x32_bf16(bias_a, z.f, acc, 0, 0, 0);
        }
        acc_[u] = acc;
    }

    // ---- P5: slot resolve (first consumption of atomic tickets) + store
#pragma unroll
    for (int u = 0; u < GPW; ++u) {
        int slot = -1;
        if (quad == 0 && e_[u] < n_edges) {
            if (r_[u] < CAP) {
                slot = pr_[u].x * CAP + r_[u];
            } else {
                int oi = atomicAdd(oflow_cnt, 1);
                if (oi < OFLOW_CAP) oflow[oi] = e_[u];
            }
        }
        // D^T: lane (quad,col) holds msgs[e=col][i=quad*4 .. +3]
        const int s = __shfl(slot, col, 64);   // from quad0 lane `col`
        if (s >= 0) {
            uint2 pkd;
            pkd.x = pack_bf16_2(acc_[u][0], acc_[u][1]);
            pkd.y = pack_bf16_2(acc_[u][2], acc_[u][3]);
            *(uint2*)(msgs + (size_t)s * DIM + quad * 4) = pkd;  // one 8B store
        }
    }
}

// ---- reduce: 32 threads/atom over fixed-stride bf16 slots, atomic-free
__global__ __launch_bounds__(256) void reduce_kernel(
    const uint16_t* __restrict__ msgs, const int* __restrict__ counts,
    float* __restrict__ out, int n_atoms)
{
    int t = blockIdx.x * blockDim.x + threadIdx.x;
    int a = t >> 5;
    if (a >= n_atoms) return;
    int c = t & 3;          // 4-col chunk (8B)
    int q = (t >> 2) & 7;   // 8-way split of the message list

    int cnt = min(counts[a * CSTR], CAP);
    const uint32_t* base = (const uint32_t*)(msgs + (size_t)a * CAP * DIM);

    float4 acc = make_float4(0.f, 0.f, 0.f, 0.f);
    for (int j = q; j < cnt; j += 8) {
        uint2 v = *(const uint2*)(base + j * 8 + c * 2);     // 4 bf16 = 8 B
        acc.x += __uint_as_float(v.x << 16);
        acc.y += __uint_as_float(v.x & 0xFFFF0000u);
        acc.z += __uint_as_float(v.y << 16);
        acc.w += __uint_as_float(v.y & 0xFFFF0000u);
    }
    // combine the 8-way q split (lane bits 2..4)
    acc.x += __shfl_xor(acc.x, 4);  acc.y += __shfl_xor(acc.y, 4);
    acc.z += __shfl_xor(acc.z, 4);  acc.w += __shfl_xor(acc.w, 4);
    acc.x += __shfl_xor(acc.x, 8);  acc.y += __shfl_xor(acc.y, 8);
    acc.z += __shfl_xor(acc.z, 8);  acc.w += __shfl_xor(acc.w, 8);
    acc.x += __shfl_xor(acc.x, 16); acc.y += __shfl_xor(acc.y, 16);
    acc.z += __shfl_xor(acc.z, 16); acc.w += __shfl_xor(acc.w, 16);
    if (q == 0)
        ((float4*)(out + (size_t)a * DIM))[c] = acc;
}

// ---- overflow fix-up (normally 0 edges): scalar f32 + atomicAdd, AFTER reduce
__global__ __launch_bounds__(256) void oflow_kernel(
    const float* __restrict__ atom, const float* __restrict__ bond,
    const int*   __restrict__ pair, const float* __restrict__ kern,
    const float* __restrict__ bias,
    const int* __restrict__ oflow_cnt, const int* __restrict__ oflow,
    float* __restrict__ out, int n_edges)
{
    int n = min(*oflow_cnt, OFLOW_CAP);
    for (int i = blockIdx.x * blockDim.x + threadIdx.x; i < n;
         i += gridDim.x * blockDim.x) {
        int e   = oflow[i];
        int dst = pair[2 * e + 0];
        int src = pair[2 * e + 1];
        float neigh[DIM], bnd[DIM], acc[DIM];
        for (int q = 0; q < DIM; ++q) neigh[q] = atom[(size_t)src * DIM + q];
        for (int q = 0; q < DIM; ++q) bnd[q]   = bond[(size_t)e * DIM + q];
#pragma unroll
        for (int ii = 0; ii < DIM; ++ii) {
            float d = 0.f;
#pragma unroll
            for (int j = 0; j < DIM; ++j) d = fmaf(bias[ii * DIM + j], neigh[j], d);
            acc[ii] = d;
        }
#pragma unroll 1
        for (int k = 0; k < DIM; ++k) {
            const float bk = bnd[k];
            const float* Kr = kern + k * (DIM * DIM);
#pragma unroll
            for (int ii = 0; ii < DIM; ++ii) {
                float d = 0.f;
#pragma unroll
                for (int j = 0; j < DIM; ++j) d = fmaf(Kr[ii * DIM + j], neigh[j], d);
                acc[ii] = fmaf(bk, d, acc[ii]);
            }
        }
#pragma unroll
        for (int ii = 0; ii < DIM; ++ii) atomicAdd(&out[(size_t)dst * DIM + ii], acc[ii]);
    }
}

// ---- safety fallback if ws too small (round-1 structure)
__global__ __launch_bounds__(256) void edge_atomic_kernel(
    const float* __restrict__ atom, const float* __restrict__ bond,
    const int*   __restrict__ pair, const float* __restrict__ kern,
    const float* __restrict__ bias, float* __restrict__ out, int n_edges)
{
    int e = blockIdx.x * blockDim.x + threadIdx.x;
    if (e >= n_edges) return;
    int dst = pair[2 * e + 0];
    int src = pair[2 * e + 1];
    float neigh[DIM], bnd[DIM], acc[DIM];
    for (int q = 0; q < DIM; ++q) neigh[q] = atom[(size_t)src * DIM + q];
    for (int q = 0; q < DIM; ++q) bnd[q]   = bond[(size_t)e * DIM + q];
#pragma unroll
    for (int i = 0; i < DIM; ++i) {
        float d = 0.f;
#pragma unroll
        for (int j = 0; j < DIM; ++j) d = fmaf(bias[i * DIM + j], neigh[j], d);
        acc[i] = d;
    }
#pragma unroll 1
    for (int k = 0; k < DIM; ++k) {
        const float bk = bnd[k];
        const float* Kr = kern + k * (DIM * DIM);
#pragma unroll
        for (int i = 0; i < DIM; ++i) {
            float d = 0.f;
#pragma unroll
            for (int j = 0; j < DIM; ++j) d = fmaf(Kr[i * DIM + j], neigh[j], d);
            acc[i] = fmaf(bk, d, acc[i]);
        }
    }
#pragma unroll
    for (int i = 0; i < DIM; ++i) atomicAdd(&out[(size_t)dst * DIM + i], acc[i]);
}

extern "C" void kernel_launch(void* const* d_in, const int* in_sizes, int n_in,
                              void* d_out, int out_size, void* d_ws, size_t ws_size,
                              hipStream_t stream)
{
    const float* atom = (const float*)d_in[0];   // (20000,16) f32
    const float* bond = (const float*)d_in[1];   // (640000,16) f32
    const int*   pair = (const int*)d_in[2];     // (640000,2) i32 [dst, src]
    const float* kern = (const float*)d_in[3];   // (16,256) f32
    const float* bias = (const float*)d_in[4];   // (256,) f32
    float*       out  = (float*)d_out;           // (20000,16) f32

    const int n_edges = in_sizes[1] / DIM;       // 640000
    const int n_atoms = in_sizes[0] / DIM;       // 20000

    // ws: counts[n_atoms*CSTR] | oflow_cnt[1] | oflow[OFLOW_CAP] | 64B | msgs bf16
    size_t counts_off = 0;
    size_t ocnt_off   = counts_off + (size_t)n_atoms * CSTR * sizeof(int);
    size_t oflow_off  = ocnt_off + sizeof(int);
    size_t msgs_off   = (oflow_off + (size_t)OFLOW_CAP * sizeof(int) + 63) & ~(size_t)63;
    size_t needed     = msgs_off + (size_t)n_atoms * CAP * DIM * sizeof(uint16_t);

    const int threads = 256;

    if (ws_size >= needed) {
        int*      counts    = (int*)((char*)d_ws + counts_off);
        int*      oflow_cnt = (int*)((char*)d_ws + ocnt_off);
        int*      oflow     = (int*)((char*)d_ws + oflow_off);
        uint16_t* msgs      = (uint16_t*)((char*)d_ws + msgs_off);

        // zero counts (padded) + oflow counter in one contiguous memset
        hipMemsetAsync(counts, 0, (size_t)n_atoms * CSTR * sizeof(int) + sizeof(int),
                       stream);

        const int n_groups = (n_edges + 15) / 16;
        const int waves    = (n_groups + GPW - 1) / GPW;
        const int mblocks  = (waves * 64 + threads - 1) / threads;
        msg_mfma_kernel<<<mblocks, threads, 0, stream>>>(
            atom, bond, pair, kern, bias, counts, oflow_cnt, oflow, msgs,
            n_edges, n_groups);

        const int rthreads = n_atoms * 32;
        reduce_kernel<<<(rthreads + threads - 1) / threads, threads, 0, stream>>>(
            msgs, counts, out, n_atoms);

        oflow_kernel<<<8, threads, 0, stream>>>(
            atom, bond, pair, kern, bias, oflow_cnt, oflow, out, n_edges);
    } else {
        hipMemsetAsync(out, 0, (size_t)out_size * sizeof(float), stream);
        edge_atomic_kernel<<<(n_edges + threads - 1) / threads, threads, 0, stream>>>(
            atom, bond, pair, kern, bias, out, n_edges);
    }
}

// Round 3
// 132.963 us; speedup vs baseline: 1.1192x; 1.0262x over previous
//
#include <hip/hip_runtime.h>
#include <stdint.h>

// EdgeNetwork, round 8: deduplicate lane addresses in msg_mfma_kernel.
// r7: staging engaged (VGPR 96) but msg only 61->55us; nothing >20% busy.
// Only model matching 55us: per-lane address processing in TA/L1 with NO
// duplicate-address merging. The quad-duplicated gathers (bond read 4x by all
// quads, atom 2x, pair 4x) issue ~580 lane-addresses per 16-edge group.
// Fix: every byte is loaded by exactly one lane, then redistributed in-wave:
//   pair: quad0-only load + shfl broadcast of src        (64 -> 16 addrs)
//   atom: chunk-permuted load cq=[0,2,1,3] + shfl_xor32  (128 -> 64)
//   bond: chunk `quad` load (coalesced 1KB/group) + 2-stage butterfly
//         (xor16, parity-select, xor32)                  (256 -> 64)
//   store: quad-pair merge via shfl_xor16 -> 16B stores  (64 -> 32)
// ~580 -> ~190 lane-addrs/group. VALU has headroom (17%) for the shuffles.
// __launch_bounds__(256,3): ~170-reg cap keeps staging, 12 waves/CU ceiling.
// History: r1 630 -> r2 CSR 333 -> r3 MFMA 190 -> r4 binning 150 -> r5 148.8
// (msg 65) -> r6 scratch-fix 147.3 (msg 61) -> r7 phase-staging 136.5 (msg 55).

constexpr int DIM  = 16;
constexpr int CAP  = 64;     // slots per atom; P(deg>64) ~ 1e-8 at Poisson(32)
constexpr int CSTR = 16;     // counts stride (ints) = one 64B line per atom
constexpr int OFLOW_CAP = 65536;
constexpr int GPW  = 4;      // 16-edge groups per wave, fully unrolled

using frag_ab = __attribute__((ext_vector_type(8))) short;   // 8 bf16
using frag_cd = __attribute__((ext_vector_type(4))) float;   // 4 f32
union ABPack { frag_ab f; uint32_t u[4]; };

__device__ __forceinline__ uint32_t pack_bf16_2(float lo, float hi) {
    // one v_perm_b32: truncate-to-bf16 pair, lo in low 16 bits
    return __builtin_amdgcn_perm(__float_as_uint(hi), __float_as_uint(lo), 0x07060302u);
}

// ---- msg kernel: fused rank + dedup gathers + MFMA(T) + packed 16B stores
__global__ __launch_bounds__(256, 3) void msg_mfma_kernel(
    const float* __restrict__ atom, const float* __restrict__ bond,
    const int*   __restrict__ pair, const float* __restrict__ kern,
    const float* __restrict__ bias,
    int* __restrict__ counts, int* __restrict__ oflow_cnt, int* __restrict__ oflow,
    uint16_t* __restrict__ msgs, int n_edges, int n_groups)
{
    const int wave = (int)((blockIdx.x * blockDim.x + threadIdx.x) >> 6);
    const int lane = threadIdx.x & 63;
    const int g0 = wave * GPW;
    if (g0 >= n_groups) return;

    const int col  = lane & 15;        // A(W): output row i | B(Z): edge e | D: col e
    const int quad = lane >> 4;        // 0..3
    const int hb   = quad >> 1;        // k parity within chunk (0/1, fixed per lane)
    const int j0   = (quad & 1) * 8;   // neigh sub-range (for W/bias frag layout)

    // ---- P1: pair loads (quad0 lanes only: 16 addrs/group) + src broadcast
    int  ec_[GPW];
    int2 pr_[GPW];
#pragma unroll
    for (int u = 0; u < GPW; ++u) {
        const int e = ((g0 + u) << 4) + col;
        ec_[u] = min(e, n_edges - 1);
        pr_[u] = make_int2(0, 0);
        if (quad == 0) pr_[u] = ((const int2*)pair)[ec_[u]];
    }
    int src_[GPW];
#pragma unroll
    for (int u = 0; u < GPW; ++u) src_[u] = __shfl(pr_[u].y, col, 64);

    // W fragments (L1-hot broadcast; overlaps P1 latency)
    frag_ab wfrag[8];
#pragma unroll
    for (int c = 0; c < 8; ++c) {
        const float* wp = kern + (2 * c + hb) * 256 + col * 16 + j0;
        float4 w0 = *(const float4*)wp;
        float4 w1 = *(const float4*)(wp + 4);
        ABPack p;
        p.u[0] = pack_bf16_2(w0.x, w0.y);
        p.u[1] = pack_bf16_2(w0.z, w0.w);
        p.u[2] = pack_bf16_2(w1.x, w1.y);
        p.u[3] = pack_bf16_2(w1.z, w1.w);
        wfrag[c] = p.f;
    }
    frag_ab bias_a;
    {
        ABPack p; p.u[0] = p.u[1] = p.u[2] = p.u[3] = 0;
        if (hb == 0) {
            const float* bp2 = bias + col * 16 + j0;
            float4 w0 = *(const float4*)bp2;
            float4 w1 = *(const float4*)(bp2 + 4);
            p.u[0] = pack_bf16_2(w0.x, w0.y);
            p.u[1] = pack_bf16_2(w0.z, w0.w);
            p.u[2] = pack_bf16_2(w1.x, w1.y);
            p.u[3] = pack_bf16_2(w1.z, w1.w);
        }
        bias_a = p.f;
    }

    // ---- P2: dedup gathers. atom: lane loads chunk cq of its col's src row
    // (cq = [0,2,1,3][quad] so one xor32 swap restores both halves).
    // bond: lane loads chunk `quad` of its col's row -> 1KB contiguous/group.
    const int cq = ((quad & 1) << 1) | (quad >> 1);   // 0,2,1,3
    float4 am_[GPW], bm_[GPW];
#pragma unroll
    for (int u = 0; u < GPW; ++u) {
        am_[u] = *(const float4*)(atom + (size_t)src_[u] * DIM + cq * 4);
        bm_[u] = *(const float4*)(bond + (size_t)ec_[u] * DIM + quad * 4);
    }

    // ---- P3: rank atomics, ticket ONLY (consumed after this group's MFMAs;
    //          issued after gathers so gather vmcnt waits exclude them)
    int r_[GPW];
#pragma unroll
    for (int u = 0; u < GPW; ++u) {
        r_[u] = CAP;
        const int e = ((g0 + u) << 4) + col;
        if (quad == 0 && e < n_edges)
            r_[u] = atomicAdd(&counts[pr_[u].x * CSTR], 1);
    }

    // ---- P4: per group: in-wave redistribute + pack + MFMA + resolve + store
#pragma unroll
    for (int u = 0; u < GPW; ++u) {
        // atom exchange: xor32 swaps chunk pairs (0<->1, 2<->3)
        float4 am = am_[u];
        float4 ao;
        ao.x = __shfl_xor(am.x, 32); ao.y = __shfl_xor(am.y, 32);
        ao.z = __shfl_xor(am.z, 32); ao.w = __shfl_xor(am.w, 32);
        // quads 0,1 hold their own low chunk; quads 2,3 get it from partner
        float nb[8];
        nb[0] = quad < 2 ? am.x : ao.x;  nb[1] = quad < 2 ? am.y : ao.y;
        nb[2] = quad < 2 ? am.z : ao.z;  nb[3] = quad < 2 ? am.w : ao.w;
        nb[4] = quad < 2 ? ao.x : am.x;  nb[5] = quad < 2 ? ao.y : am.y;
        nb[6] = quad < 2 ? ao.z : am.z;  nb[7] = quad < 2 ? ao.w : am.w;

        // bond butterfly: stage1 xor16 pairs chunks within a half
        float4 bm = bm_[u];
        float4 bo;
        bo.x = __shfl_xor(bm.x, 16); bo.y = __shfl_xor(bm.y, 16);
        bo.z = __shfl_xor(bm.z, 16); bo.w = __shfl_xor(bm.w, 16);
        float4 cA, cB;   // even / odd chunk of this lane's half
        cA.x = (quad & 1) ? bo.x : bm.x; cA.y = (quad & 1) ? bo.y : bm.y;
        cA.z = (quad & 1) ? bo.z : bm.z; cA.w = (quad & 1) ? bo.w : bm.w;
        cB.x = (quad & 1) ? bm.x : bo.x; cB.y = (quad & 1) ? bm.y : bo.y;
        cB.z = (quad & 1) ? bm.z : bo.z; cB.w = (quad & 1) ? bm.w : bo.w;
        // own-parity (hb) selection, and partner-parity (1-hb) to give away
        float s0 = hb ? cA.y : cA.x,  s1 = hb ? cA.w : cA.z;
        float s2 = hb ? cB.y : cB.x,  s3 = hb ? cB.w : cB.z;
        float g0v = hb ? cA.x : cA.y, g1v = hb ? cA.z : cA.w;
        float g2v = hb ? cB.x : cB.y, g3v = hb ? cB.z : cB.w;
        // stage2 xor32: partner (hb^1) prepared OUR parity of the other half
        float t0 = __shfl_xor(g0v, 32), t1 = __shfl_xor(g1v, 32);
        float t2 = __shfl_xor(g2v, 32), t3 = __shfl_xor(g3v, 32);
        float bks[8];
        bks[0] = quad < 2 ? s0 : t0;  bks[1] = quad < 2 ? s1 : t1;
        bks[2] = quad < 2 ? s2 : t2;  bks[3] = quad < 2 ? s3 : t3;
        bks[4] = quad < 2 ? t0 : s0;  bks[5] = quad < 2 ? t1 : s1;
        bks[6] = quad < 2 ? t2 : s2;  bks[7] = quad < 2 ? t3 : s3;

        frag_cd acc = {0.f, 0.f, 0.f, 0.f};
#pragma unroll
        for (int c = 0; c < 8; ++c) {
            const float bk = bks[c];
            ABPack z;
            z.u[0] = pack_bf16_2(bk * nb[0], bk * nb[1]);
            z.u[1] = pack_bf16_2(bk * nb[2], bk * nb[3]);
            z.u[2] = pack_bf16_2(bk * nb[4], bk * nb[5]);
            z.u[3] = pack_bf16_2(bk * nb[6], bk * nb[7]);
            // operand swap: D = W^T Z^T -> lane holds 4 consecutive cols
            acc = __builtin_amdgcn_mfma_f32_16x16x32_bf16(wfrag[c], z.f, acc, 0, 0, 0);
        }
        { // bias chunk (k<16 half only)
            ABPack z; z.u[0] = z.u[1] = z.u[2] = z.u[3] = 0;
            if (hb == 0) {
                z.u[0] = pack_bf16_2(nb[0], nb[1]);
                z.u[1] = pack_bf16_2(nb[2], nb[3]);
                z.u[2] = pack_bf16_2(nb[4], nb[5]);
                z.u[3] = pack_bf16_2(nb[6], nb[7]);
            }
            acc = __builtin_amdgcn_mfma_f32_16x16x32_bf16(bias_a, z.f, acc, 0, 0, 0);
        }

        // resolve slot (first consumption of this group's atomic ticket)
        int slot = -1;
        const int e = ((g0 + u) << 4) + col;
        if (quad == 0 && e < n_edges) {
            if (r_[u] < CAP) {
                slot = pr_[u].x * CAP + r_[u];
            } else {
                int oi = atomicAdd(oflow_cnt, 1);
                if (oi < OFLOW_CAP) oflow[oi] = e;
            }
        }
        const int s = __shfl(slot, col, 64);   // broadcast from quad0 lane `col`

        // D^T: lane (quad,col) holds msgs[e=col][i=quad*4 .. +3].
        // Merge quad pairs (xor16) so quads 0,2 issue one 16B store each.
        uint2 pkd;
        pkd.x = pack_bf16_2(acc[0], acc[1]);
        pkd.y = pack_bf16_2(acc[2], acc[3]);
        uint32_t qx = __shfl_xor(pkd.x, 16);
        uint32_t qy = __shfl_xor(pkd.y, 16);
        if (s >= 0 && (quad & 1) == 0) {
            uint4 w4 = make_uint4(pkd.x, pkd.y, qx, qy);
            *(uint4*)(msgs + (size_t)s * DIM + (quad & 2) * 4) = w4;
        }
    }
}

// ---- reduce: 32 threads/atom over fixed-stride bf16 slots, atomic-free
__global__ __launch_bounds__(256) void reduce_kernel(
    const uint16_t* __restrict__ msgs, const int* __restrict__ counts,
    float* __restrict__ out, int n_atoms)
{
    int t = blockIdx.x * blockDim.x + threadIdx.x;
    int a = t >> 5;
    if (a >= n_atoms) return;
    int c = t & 3;          // 4-col chunk (8B)
    int q = (t >> 2) & 7;   // 8-way split of the message list

    int cnt = min(counts[a * CSTR], CAP);
    const uint32_t* base = (const uint32_t*)(msgs + (size_t)a * CAP * DIM);

    float4 acc = make_float4(0.f, 0.f, 0.f, 0.f);
    for (int j = q; j < cnt; j += 8) {
        uint2 v = *(const uint2*)(base + j * 8 + c * 2);     // 4 bf16 = 8 B
        acc.x += __uint_as_float(v.x << 16);
        acc.y += __uint_as_float(v.x & 0xFFFF0000u);
        acc.z += __uint_as_float(v.y << 16);
        acc.w += __uint_as_float(v.y & 0xFFFF0000u);
    }
    // combine the 8-way q split (lane bits 2..4)
    acc.x += __shfl_xor(acc.x, 4);  acc.y += __shfl_xor(acc.y, 4);
    acc.z += __shfl_xor(acc.z, 4);  acc.w += __shfl_xor(acc.w, 4);
    acc.x += __shfl_xor(acc.x, 8);  acc.y += __shfl_xor(acc.y, 8);
    acc.z += __shfl_xor(acc.z, 8);  acc.w += __shfl_xor(acc.w, 8);
    acc.x += __shfl_xor(acc.x, 16); acc.y += __shfl_xor(acc.y, 16);
    acc.z += __shfl_xor(acc.z, 16); acc.w += __shfl_xor(acc.w, 16);
    if (q == 0)
        ((float4*)(out + (size_t)a * DIM))[c] = acc;
}

// ---- overflow fix-up (normally 0 edges): scalar f32 + atomicAdd, AFTER reduce
__global__ __launch_bounds__(256) void oflow_kernel(
    const float* __restrict__ atom, const float* __restrict__ bond,
    const int*   __restrict__ pair, const float* __restrict__ kern,
    const float* __restrict__ bias,
    const int* __restrict__ oflow_cnt, const int* __restrict__ oflow,
    float* __restrict__ out, int n_edges)
{
    int n = min(*oflow_cnt, OFLOW_CAP);
    for (int i = blockIdx.x * blockDim.x + threadIdx.x; i < n;
         i += gridDim.x * blockDim.x) {
        int e   = oflow[i];
        int dst = pair[2 * e + 0];
        int src = pair[2 * e + 1];
        float neigh[DIM], bnd[DIM], acc[DIM];
        for (int q = 0; q < DIM; ++q) neigh[q] = atom[(size_t)src * DIM + q];
        for (int q = 0; q < DIM; ++q) bnd[q]   = bond[(size_t)e * DIM + q];
#pragma unroll
        for (int ii = 0; ii < DIM; ++ii) {
            float d = 0.f;
#pragma unroll
            for (int j = 0; j < DIM; ++j) d = fmaf(bias[ii * DIM + j], neigh[j], d);
            acc[ii] = d;
        }
#pragma unroll 1
        for (int k = 0; k < DIM; ++k) {
            const float bk = bnd[k];
            const float* Kr = kern + k * (DIM * DIM);
#pragma unroll
            for (int ii = 0; ii < DIM; ++ii) {
                float d = 0.f;
#pragma unroll
                for (int j = 0; j < DIM; ++j) d = fmaf(Kr[ii * DIM + j], neigh[j], d);
                acc[ii] = fmaf(bk, d, acc[ii]);
            }
        }
#pragma unroll
        for (int ii = 0; ii < DIM; ++ii) atomicAdd(&out[(size_t)dst * DIM + ii], acc[ii]);
    }
}

// ---- safety fallback if ws too small (round-1 structure)
__global__ __launch_bounds__(256) void edge_atomic_kernel(
    const float* __restrict__ atom, const float* __restrict__ bond,
    const int*   __restrict__ pair, const float* __restrict__ kern,
    const float* __restrict__ bias, float* __restrict__ out, int n_edges)
{
    int e = blockIdx.x * blockDim.x + threadIdx.x;
    if (e >= n_edges) return;
    int dst = pair[2 * e + 0];
    int src = pair[2 * e + 1];
    float neigh[DIM], bnd[DIM], acc[DIM];
    for (int q = 0; q < DIM; ++q) neigh[q] = atom[(size_t)src * DIM + q];
    for (int q = 0; q < DIM; ++q) bnd[q]   = bond[(size_t)e * DIM + q];
#pragma unroll
    for (int i = 0; i < DIM; ++i) {
        float d = 0.f;
#pragma unroll
        for (int j = 0; j < DIM; ++j) d = fmaf(bias[i * DIM + j], neigh[j], d);
        acc[i] = d;
    }
#pragma unroll 1
    for (int k = 0; k < DIM; ++k) {
        const float bk = bnd[k];
        const float* Kr = kern + k * (DIM * DIM);
#pragma unroll
        for (int i = 0; i < DIM; ++i) {
            float d = 0.f;
#pragma unroll
            for (int j = 0; j < DIM; ++j) d = fmaf(Kr[i * DIM + j], neigh[j], d);
            acc[i] = fmaf(bk, d, acc[i]);
        }
    }
#pragma unroll
    for (int i = 0; i < DIM; ++i) atomicAdd(&out[(size_t)dst * DIM + i], acc[i]);
}

extern "C" void kernel_launch(void* const* d_in, const int* in_sizes, int n_in,
                              void* d_out, int out_size, void* d_ws, size_t ws_size,
                              hipStream_t stream)
{
    const float* atom = (const float*)d_in[0];   // (20000,16) f32
    const float* bond = (const float*)d_in[1];   // (640000,16) f32
    const int*   pair = (const int*)d_in[2];     // (640000,2) i32 [dst, src]
    const float* kern = (const float*)d_in[3];   // (16,256) f32
    const float* bias = (const float*)d_in[4];   // (256,) f32
    float*       out  = (float*)d_out;           // (20000,16) f32

    const int n_edges = in_sizes[1] / DIM;       // 640000
    const int n_atoms = in_sizes[0] / DIM;       // 20000

    // ws: counts[n_atoms*CSTR] | oflow_cnt[1] | oflow[OFLOW_CAP] | 64B | msgs bf16
    size_t counts_off = 0;
    size_t ocnt_off   = counts_off + (size_t)n_atoms * CSTR * sizeof(int);
    size_t oflow_off  = ocnt_off + sizeof(int);
    size_t msgs_off   = (oflow_off + (size_t)OFLOW_CAP * sizeof(int) + 63) & ~(size_t)63;
    size_t needed     = msgs_off + (size_t)n_atoms * CAP * DIM * sizeof(uint16_t);

    const int threads = 256;

    if (ws_size >= needed) {
        int*      counts    = (int*)((char*)d_ws + counts_off);
        int*      oflow_cnt = (int*)((char*)d_ws + ocnt_off);
        int*      oflow     = (int*)((char*)d_ws + oflow_off);
        uint16_t* msgs      = (uint16_t*)((char*)d_ws + msgs_off);

        // zero counts (padded) + oflow counter in one contiguous memset
        hipMemsetAsync(counts, 0, (size_t)n_atoms * CSTR * sizeof(int) + sizeof(int),
                       stream);

        const int n_groups = (n_edges + 15) / 16;
        const int waves    = (n_groups + GPW - 1) / GPW;
        const int mblocks  = (waves * 64 + threads - 1) / threads;
        msg_mfma_kernel<<<mblocks, threads, 0, stream>>>(
            atom, bond, pair, kern, bias, counts, oflow_cnt, oflow, msgs,
            n_edges, n_groups);

        const int rthreads = n_atoms * 32;
        reduce_kernel<<<(rthreads + threads - 1) / threads, threads, 0, stream>>>(
            msgs, counts, out, n_atoms);

        oflow_kernel<<<8, threads, 0, stream>>>(
            atom, bond, pair, kern, bias, oflow_cnt, oflow, out, n_edges);
    } else {
        hipMemsetAsync(out, 0, (size_t)out_size * sizeof(float), stream);
        edge_atomic_kernel<<<(n_edges + threads - 1) / threads, threads, 0, stream>>>(
            atom, bond, pair, kern, bias, out, n_edges);
    }
}